// Round 23
// baseline (259.275 us; speedup 1.0000x reference)
//
#include <hip/hip_runtime.h>

// ---------------------------------------------------------------------------
// Types
// ---------------------------------------------------------------------------
using bf16x8 = __attribute__((ext_vector_type(8))) __bf16;
using f32x4  = __attribute__((ext_vector_type(4))) float;

#define AS1(p) (const __attribute__((address_space(1))) void*)(p)
#define AS3(p) (__attribute__((address_space(3))) void*)(p)

__device__ __forceinline__ unsigned short f2bf(float f) {
    unsigned int u = __float_as_uint(f);
    unsigned int r = (u + 0x7FFFu + ((u >> 16) & 1u)) >> 16;
    return (unsigned short)r;
}
__device__ __forceinline__ float bf2f(unsigned short u) {
    return __uint_as_float((unsigned int)u << 16);
}
// tanh-form GELU: x*sigmoid(1.5957691*(x+0.044715x^3)); |err vs erf-GELU|<4e-4
__device__ __forceinline__ float gelu_fast(float x) {
    const float a = 1.5957691f * (x + 0.044715f * x * x * x);
    return x / (1.0f + __expf(-a));
}

// ---------------------------------------------------------------------------
// Fused fp32 -> bf16 convert for all 5 weight tensors (single launch).
// Segments (in 1024-elem blocks): qk_w 2048 | v_w 1024 | out_w 1024 |
// w1 4096 | w2 4096  -> 12288 blocks total. Branch is block-uniform.
// ---------------------------------------------------------------------------
__global__ __launch_bounds__(256)
void cvt5_kernel(const float* __restrict__ s0, unsigned short* __restrict__ d0,
                 const float* __restrict__ s1, unsigned short* __restrict__ d1,
                 const float* __restrict__ s2, unsigned short* __restrict__ d2,
                 const float* __restrict__ s3, unsigned short* __restrict__ d3,
                 const float* __restrict__ s4, unsigned short* __restrict__ d4) {
    const int b = blockIdx.x;
    const float* s; unsigned short* d; int base;
    if (b < 2048)      { s = s0; d = d0; base = 0; }
    else if (b < 3072) { s = s1; d = d1; base = 2048; }
    else if (b < 4096) { s = s2; d = d2; base = 3072; }
    else if (b < 8192) { s = s3; d = d3; base = 4096; }
    else               { s = s4; d = d4; base = 8192; }
    const int i = (b - base) * 1024 + threadIdx.x * 4;
    const float4 v = *(const float4*)(s + i);
    *(ushort4*)(d + i) = make_ushort4(f2bf(v.x), f2bf(v.y), f2bf(v.z), f2bf(v.w));
}

// ---------------------------------------------------------------------------
// LayerNorm: one 1024-wide row per block (256 threads x 4 elems), bf16 out
// ---------------------------------------------------------------------------
__global__ __launch_bounds__(256) void ln_kernel(const float* __restrict__ in,
                                                 const float* __restrict__ w,
                                                 const float* __restrict__ b,
                                                 unsigned short* __restrict__ out) {
    const int row = blockIdx.x;
    const int tid = threadIdx.x;
    const float4 v = *(const float4*)(in + (size_t)row * 1024 + tid * 4);
    float s  = v.x + v.y + v.z + v.w;
    float ss = v.x * v.x + v.y * v.y + v.z * v.z + v.w * v.w;
    #pragma unroll
    for (int m = 1; m < 64; m <<= 1) {
        s  += __shfl_xor(s, m, 64);
        ss += __shfl_xor(ss, m, 64);
    }
    __shared__ float red[8];
    if ((tid & 63) == 0) { red[(tid >> 6) * 2] = s; red[(tid >> 6) * 2 + 1] = ss; }
    __syncthreads();
    s  = red[0] + red[2] + red[4] + red[6];
    ss = red[1] + red[3] + red[5] + red[7];
    const float mu  = s * (1.0f / 1024.0f);
    const float var = ss * (1.0f / 1024.0f) - mu * mu;
    const float rstd = rsqrtf(var + 1e-5f);
    const float4 wv = *(const float4*)(w + tid * 4);
    const float4 bv = *(const float4*)(b + tid * 4);
    ushort4 o;
    o.x = f2bf((v.x - mu) * rstd * wv.x + bv.x);
    o.y = f2bf((v.y - mu) * rstd * wv.y + bv.y);
    o.z = f2bf((v.z - mu) * rstd * wv.z + bv.z);
    o.w = f2bf((v.w - mu) * rstd * wv.w + bv.w);
    *(ushort4*)(out + (size_t)row * 1024 + tid * 4) = o;
}

// ---------------------------------------------------------------------------
// GEMM (128x128 tile, round-10/11 verified): 4 waves, BK=128, single-buffer
// 2-barrier loop, 16-slot XOR swizzle, T1 XCD-chunked block swizzle.
// EPI: 0=QK mix, 1=V mix+transpose, 2=(out-proj|mlp2)+resid
// ---------------------------------------------------------------------------
template <int EPI>
__global__ __launch_bounds__(256, 2)
void gemm_bt(const unsigned short* __restrict__ A,
             const unsigned short* __restrict__ W,
             const float* __restrict__ bias,
             int M, int N, int K,
             const float* __restrict__ e0, const float* __restrict__ e1,
             float* __restrict__ o0, float* __restrict__ o1,
             unsigned short* __restrict__ u0, unsigned short* __restrict__ u1) {
    __shared__ unsigned short As[128 * 128];   // 32KB, [row][128 elems=256B]
    __shared__ unsigned short Bs[128 * 128];   // 32KB
    const int tid  = threadIdx.x;
    const int wave = tid >> 6, lane = tid & 63;
    const int wr = wave >> 1, wc = wave & 1;
    const int q15 = lane & 15, g = lane >> 4;

    const int gx = gridDim.x;
    const int nwg = gx * gridDim.y;
    int flat = blockIdx.y * gx + blockIdx.x;
    flat = (flat & 7) * (nwg >> 3) + (flat >> 3);
    const int gm0 = (flat / gx) * 128, gn0 = (flat % gx) * 128;

    f32x4 acc[4][4] = {};

    const int lrow4 = lane >> 4;            // 0..3 row within instr
    const int lslot = lane & 15;            // 16B slot within 256B row
    const int rswz  = q15 << 4;             // read-side XOR bytes ((row&15)<<4)

    for (int k0 = 0; k0 < K; k0 += 128) {
        #pragma unroll
        for (int i = 0; i < 8; ++i) {
            const int row  = wave * 32 + i * 4 + lrow4;
            const int selm = (lslot ^ (row & 15)) << 3;   // element offset
            __builtin_amdgcn_global_load_lds(AS1(A + (size_t)(gm0 + row) * K + k0 + selm),
                                             AS3((char*)As + wave * 8192 + i * 1024), 16, 0, 0);
            __builtin_amdgcn_global_load_lds(AS1(W + (size_t)(gn0 + row) * K + k0 + selm),
                                             AS3((char*)Bs + wave * 8192 + i * 1024), 16, 0, 0);
        }
        __syncthreads();
        #pragma unroll
        for (int kk = 0; kk < 4; ++kk) {
            bf16x8 af[4], bfr[4];
            #pragma unroll
            for (int m = 0; m < 4; ++m)
                af[m] = *(const bf16x8*)((char*)As + (wr * 64 + m * 16 + q15) * 256 +
                                         ((kk * 64 + g * 16) ^ rswz));
            #pragma unroll
            for (int n = 0; n < 4; ++n)
                bfr[n] = *(const bf16x8*)((char*)Bs + (wc * 64 + n * 16 + q15) * 256 +
                                          ((kk * 64 + g * 16) ^ rswz));
            #pragma unroll
            for (int m = 0; m < 4; ++m)
                #pragma unroll
                for (int n = 0; n < 4; ++n)
                    acc[m][n] = __builtin_amdgcn_mfma_f32_16x16x32_bf16(af[m], bfr[n], acc[m][n], 0, 0, 0);
        }
        __syncthreads();
    }

    #pragma unroll
    for (int m = 0; m < 4; ++m)
    #pragma unroll
    for (int n = 0; n < 4; ++n)
    #pragma unroll
    for (int j = 0; j < 4; ++j) {
        const int r = gm0 + wr * 64 + m * 16 + g * 4 + j;
        const int c = gn0 + wc * 64 + n * 16 + q15;
        const float val = acc[m][n][j] + bias[c];
        if constexpr (EPI == 0) {            // qk: mix with Query/Key inputs
            const int bb = r >> 10, nn = r & 1023;
            const int h = c >> 7, hs = (c >> 1) & 63, isk = c & 1;
            const size_t idx = (((size_t)(bb * 16 + h)) * 1024 + nn) * 64 + hs;
            if (!isk) { const float mx = 0.7f * val + 0.3f * e0[idx]; o0[idx] = mx; u0[idx] = f2bf(mx); }
            else      { const float mx = 0.7f * val + 0.3f * e1[idx]; o1[idx] = mx; u1[idx] = f2bf(mx); }
        } else if constexpr (EPI == 1) {     // v: mix + write transposed bf16
            const int bb = r >> 10, nn = r & 1023;
            const int h = c >> 6, hs = c & 63;
            const size_t idx = (((size_t)(bb * 16 + h)) * 1024 + nn) * 64 + hs;
            const float mx = 0.7f * val + 0.3f * e0[idx];
            o0[idx] = mx;
            u0[(((size_t)(bb * 16 + h)) * 64 + hs) * 1024 + nn] = f2bf(mx);
        } else {                             // +residual -> fp32
            const size_t idx = (size_t)r * N + c;
            o0[idx] = val + e0[idx];
        }
    }
}

// ---------------------------------------------------------------------------
// PIPELINED BIG GEMM (mlp1): 256x256 tile, 8 waves (2Mx4N), BK=32,
// 3-RING LDS (96KB), counted vmcnt(4) + one s_barrier per K-tile
// (R14-verified schedule & swizzle).  Epilogue: GELU -> bf16.
// ---------------------------------------------------------------------------
__global__ __launch_bounds__(512, 1)
void gemm_big_gelu(const unsigned short* __restrict__ A,
                   const unsigned short* __restrict__ W,
                   const float* __restrict__ bias,
                   int M, int N, int K,
                   unsigned short* __restrict__ u0) {
    __shared__ unsigned short Ls[3][2][256 * 32];   // 96KB
    const int tid  = threadIdx.x;
    const int wave = tid >> 6, lane = tid & 63;
    const int wr = wave >> 2, wc = wave & 3;        // 2M x 4N
    const int q15 = lane & 15, g = lane >> 4;       // g = k-slot 0..3

    const int gx = gridDim.x;
    const int nwg = gx * gridDim.y;
    int flat = blockIdx.y * gx + blockIdx.x;
    flat = (flat & 7) * (nwg >> 3) + (flat >> 3);
    const int gm0 = (flat / gx) * 256, gn0 = (flat % gx) * 256;

    f32x4 acc[8][4] = {};

    const int srow  = tid >> 2;                        // 0..127
    const int sslot = (tid & 3) ^ ((srow >> 1) & 3);
    const int selm  = sslot << 3;                      // element offset

    #define STAGEH(kt, p, rb)                                                        \
        {                                                                            \
            const unsigned short* src_ = ((p) < 2) ? A : W;                          \
            const int gbase_ = ((p) < 2) ? gm0 : gn0;                                \
            const int row_ = ((p) & 1) * 128 + srow;                                 \
            __builtin_amdgcn_global_load_lds(                                        \
                AS1(src_ + (size_t)(gbase_ + row_) * K + (kt) * 32 + selm),          \
                AS3((char*)Ls[rb][(p) >> 1] + ((p) & 1) * 8192 + tid * 16),          \
                16, 0, 0);                                                           \
        }

    const int nt = K >> 5;
    #pragma unroll
    for (int p = 0; p < 4; ++p) STAGEH(0, p, 0);
    #pragma unroll
    for (int p = 0; p < 4; ++p) STAGEH(1, p, 1);

    int rb = 0;
    for (int t = 0; t < nt; ++t) {
        if (t >= nt - 1) { asm volatile("s_waitcnt vmcnt(0)" ::: "memory"); }
        else             { asm volatile("s_waitcnt vmcnt(4)" ::: "memory"); }
        asm volatile("s_barrier" ::: "memory");
        const int rb2 = (rb >= 1) ? rb - 1 : rb + 2;   // (rb+2)%3
        const char* Ab = (const char*)Ls[rb][0];
        const char* Bb = (const char*)Ls[rb][1];
        #pragma unroll
        for (int p = 0; p < 4; ++p) {                  // quadrant (mh,nh)
            if (t + 2 < nt) STAGEH(t + 2, p, rb2);
            const int mh = p >> 1, nh = p & 1;
            bf16x8 af[4], bf[2];
            #pragma unroll
            for (int mm = 0; mm < 4; ++mm) {
                const int row = wr * 128 + mh * 64 + mm * 16 + q15;
                af[mm] = *(const bf16x8*)(Ab + row * 64 + ((g ^ ((row >> 1) & 3)) << 4));
            }
            #pragma unroll
            for (int nn = 0; nn < 2; ++nn) {
                const int row = wc * 64 + nh * 32 + nn * 16 + q15;
                bf[nn] = *(const bf16x8*)(Bb + row * 64 + ((g ^ ((row >> 1) & 3)) << 4));
            }
            __builtin_amdgcn_s_setprio(1);
            #pragma unroll
            for (int mm = 0; mm < 4; ++mm)
                #pragma unroll
                for (int nn = 0; nn < 2; ++nn)
                    acc[mh * 4 + mm][nh * 2 + nn] = __builtin_amdgcn_mfma_f32_16x16x32_bf16(
                        af[mm], bf[nn], acc[mh * 4 + mm][nh * 2 + nn], 0, 0, 0);
            __builtin_amdgcn_s_setprio(0);
        }
        rb = (rb == 2) ? 0 : rb + 1;
    }
    #undef STAGEH

    #pragma unroll
    for (int m = 0; m < 8; ++m)
    #pragma unroll
    for (int n = 0; n < 4; ++n)
    #pragma unroll
    for (int j = 0; j < 4; ++j) {
        const int r = gm0 + wr * 128 + m * 16 + g * 4 + j;
        const int c = gn0 + wc * 64 + n * 16 + q15;
        const float val = acc[m][n][j] + bias[c];
        u0[(size_t)r * N + c] = f2bf(gelu_fast(val));
    }
}

// ---------------------------------------------------------------------------
// Flash attention, split-KV x2, LDS-staged K/V, swapped-QK^T in-reg softmax.
// grid (N/64, B*H, 2), 256 threads = 4 waves x 16 q-rows.  (round-5 verified)
// + T5 s_setprio around MFMA clusters (6 blocks/CU at independent phases).
// ---------------------------------------------------------------------------
__global__ __launch_bounds__(256, 6)
void attn_kernel(const unsigned short* __restrict__ Qb,
                 const unsigned short* __restrict__ Kb,
                 const unsigned short* __restrict__ Vt,
                 unsigned short* __restrict__ Op,   // [2][64][1024][64] bf16
                 float* __restrict__ Mws,           // [2][64][1024]
                 float* __restrict__ Lws) {         // [2][64][1024]
    const int bh = blockIdx.y;
    const int z  = blockIdx.z;
    const int tid = threadIdx.x, wave = tid >> 6, lane = tid & 63;
    const int qbase = blockIdx.x * 64 + wave * 16;
    const int q15 = lane & 15, g = lane >> 4;

    const unsigned short* Qh = Qb + (size_t)bh * 1024 * 64;
    const unsigned short* Kh = Kb + (size_t)bh * 1024 * 64;
    const unsigned short* Vh = Vt + (size_t)bh * 64 * 1024;

    __shared__ alignas(128) unsigned short Ks[64 * 64];   // 8KB
    __shared__ alignas(128) unsigned short Vs[64 * 64];   // 8KB
    __shared__ alignas(128) unsigned short Ps[4][1024];   // 8KB (2KB/wave)
    char* const Pb = (char*)Ps[wave] + q15 * 128;
    const int swz = (q15 & 7) << 4;

    const int srow8 = lane >> 3;                       // 0..7
    const int selm  = (((lane & 7) ^ srow8) << 3);     // pre-swizzled element

    bf16x8 aq[2];
    aq[0] = *(const bf16x8*)&Qh[(size_t)(qbase + q15) * 64 + 0  + g * 8];
    aq[1] = *(const bf16x8*)&Qh[(size_t)(qbase + q15) * 64 + 32 + g * 8];

    f32x4 o[4] = {};
    float mrow = -1e30f, lrow = 0.f;

    const int t0 = z * 8;
    for (int t = t0; t < t0 + 8; ++t) {
        const int kb = t * 64;
        #pragma unroll
        for (int i = 0; i < 2; ++i) {
            const int r = wave * 16 + i * 8 + srow8;
            __builtin_amdgcn_global_load_lds(AS1(Kh + (size_t)(kb + r) * 64 + selm),
                                             AS3((char*)Ks + wave * 2048 + i * 1024), 16, 0, 0);
            __builtin_amdgcn_global_load_lds(AS1(Vh + (size_t)r * 1024 + kb + selm),
                                             AS3((char*)Vs + wave * 2048 + i * 1024), 16, 0, 0);
        }
        __syncthreads();

        f32x4 s[4] = {};
        __builtin_amdgcn_s_setprio(1);
        #pragma unroll
        for (int kt = 0; kt < 4; ++kt) {
            #pragma unroll
            for (int kk = 0; kk < 2; ++kk) {
                const bf16x8 bk = *(const bf16x8*)((char*)Ks + (kt * 16 + q15) * 128 +
                                                   ((kk * 64 + g * 16) ^ swz));
                s[kt] = __builtin_amdgcn_mfma_f32_16x16x32_bf16(bk, aq[kk], s[kt], 0, 0, 0);
            }
        }
        __builtin_amdgcn_s_setprio(0);
        float pm = -1e30f;
        #pragma unroll
        for (int kt = 0; kt < 4; ++kt) {
            s[kt] *= 0.125f;
            pm = fmaxf(pm, fmaxf(fmaxf(s[kt][0], s[kt][1]), fmaxf(s[kt][2], s[kt][3])));
        }
        pm = fmaxf(pm, __shfl_xor(pm, 16, 64));
        pm = fmaxf(pm, __shfl_xor(pm, 32, 64));
        const float mnew = fmaxf(mrow, pm);
        const float alpha = __expf(mrow - mnew);
        mrow = mnew;

        float rs = 0.f;
        #pragma unroll
        for (int kt = 0; kt < 4; ++kt) {
            const float p0 = __expf(s[kt][0] - mnew);
            const float p1 = __expf(s[kt][1] - mnew);
            const float p2 = __expf(s[kt][2] - mnew);
            const float p3 = __expf(s[kt][3] - mnew);
            rs += (p0 + p1) + (p2 + p3);
            uint2 pk;
            pk.x = (unsigned int)f2bf(p0) | ((unsigned int)f2bf(p1) << 16);
            pk.y = (unsigned int)f2bf(p2) | ((unsigned int)f2bf(p3) << 16);
            *(uint2*)(Pb + (((kt * 32 + g * 8) ^ swz))) = pk;
        }
        rs += __shfl_xor(rs, 16, 64);
        rs += __shfl_xor(rs, 32, 64);
        lrow = lrow * alpha + rs;

        float af[4];
        #pragma unroll
        for (int j = 0; j < 4; ++j) af[j] = __shfl(alpha, g * 4 + j, 64);
        #pragma unroll
        for (int dt = 0; dt < 4; ++dt)
            #pragma unroll
            for (int j = 0; j < 4; ++j) o[dt][j] *= af[j];

        __builtin_amdgcn_s_setprio(1);
        #pragma unroll
        for (int Bb = 0; Bb < 2; ++Bb) {
            const bf16x8 pa = *(const bf16x8*)(Pb + (((Bb * 64 + g * 16) ^ swz)));
            #pragma unroll
            for (int dt = 0; dt < 4; ++dt) {
                const bf16x8 vb = *(const bf16x8*)((char*)Vs + (dt * 16 + q15) * 128 +
                                                   ((Bb * 64 + g * 16) ^ swz));
                o[dt] = __builtin_amdgcn_mfma_f32_16x16x32_bf16(pa, vb, o[dt], 0, 0, 0);
            }
        }
        __builtin_amdgcn_s_setprio(0);
        __syncthreads();
    }

    #pragma unroll
    for (int dt = 0; dt < 4; ++dt)
        #pragma unroll
        for (int j = 0; j < 4; ++j) {
            const int q = qbase + g * 4 + j;
            Op[(((size_t)z * 64 + bh) * 1024 + q) * 64 + dt * 16 + q15] = f2bf(o[dt][j]);
        }
    if (g == 0) {
        const size_t mi = ((size_t)z * 64 + bh) * 1024 + qbase + q15;
        Mws[mi] = mrow;
        Lws[mi] = lrow;
    }
}

// ---------------------------------------------------------------------------
// Combine the two kv-halves
// ---------------------------------------------------------------------------
__global__ __launch_bounds__(256)
void attn_combine(const unsigned short* __restrict__ Op,
                  const float* __restrict__ Mws,
                  const float* __restrict__ Lws,
                  unsigned short* __restrict__ Ob) {
    const int e4 = blockIdx.x * 256 + threadIdx.x;
    const int d0 = (e4 & 15) * 4;
    const int q  = (e4 >> 4) & 1023;
    const int bh = e4 >> 14;
    const size_t base0 = (((size_t)bh) * 1024 + q) * 64 + d0;
    const size_t base1 = (((size_t)(64 + bh)) * 1024 + q) * 64 + d0;
    const ushort4 a = *(const ushort4*)&Op[base0];
    const ushort4 c = *(const ushort4*)&Op[base1];
    const size_t mi0 = (size_t)bh * 1024 + q;
    const size_t mi1 = mi0 + 64 * 1024;
    const float m0 = Mws[mi0], m1 = Mws[mi1];
    const float l0 = Lws[mi0], l1 = Lws[mi1];
    const float m  = fmaxf(m0, m1);
    const float w0 = __expf(m0 - m), w1 = __expf(m1 - m);
    const float inv = 1.0f / (l0 * w0 + l1 * w1);
    ushort4 r;
    r.x = f2bf((bf2f(a.x) * w0 + bf2f(c.x) * w1) * inv);
    r.y = f2bf((bf2f(a.y) * w0 + bf2f(c.y) * w1) * inv);
    r.z = f2bf((bf2f(a.z) * w0 + bf2f(c.z) * w1) * inv);
    r.w = f2bf((bf2f(a.w) * w0 + bf2f(c.w) * w1) * inv);
    const int b = bh >> 4, h = bh & 15;
    *(ushort4*)&Ob[((size_t)(b * 1024 + q)) * 1024 + h * 64 + d0] = r;
}

// ---------------------------------------------------------------------------
// Launch  (R22 best configuration + T5 setprio in attn)
// ---------------------------------------------------------------------------
extern "C" void kernel_launch(void* const* d_in, const int* in_sizes, int n_in,
                              void* d_out, int out_size, void* d_ws, size_t ws_size,
                              hipStream_t stream) {
    (void)in_sizes; (void)n_in; (void)out_size; (void)ws_size;
    const float* x     = (const float*)d_in[0];
    const float* Qin   = (const float*)d_in[1];
    const float* Kin   = (const float*)d_in[2];
    const float* Vin   = (const float*)d_in[3];
    const float* ln_w  = (const float*)d_in[4];
    const float* ln_b  = (const float*)d_in[5];
    const float* qk_w  = (const float*)d_in[6];
    const float* qk_b  = (const float*)d_in[7];
    const float* v_w   = (const float*)d_in[8];
    const float* v_b   = (const float*)d_in[9];
    const float* out_w = (const float*)d_in[10];
    const float* out_b = (const float*)d_in[11];
    const float* w1    = (const float*)d_in[12];
    const float* b1    = (const float*)d_in[13];
    const float* w2    = (const float*)d_in[14];
    const float* b2    = (const float*)d_in[15];

    const size_t FOUR_M = (size_t)4 * 1024 * 1024;
    float* out0 = (float*)d_out;
    float* Qout = out0 + FOUR_M;
    float* Kout = Qout + FOUR_M;
    float* Vout = Kout + FOUR_M;

    char* ws = (char*)d_ws;
    const size_t MB = 1024 * 1024;
    unsigned short* xn   = (unsigned short*)(ws + 0);        // 8MB (reused as xn2)
    unsigned short* qkwb = (unsigned short*)(ws + 8 * MB);   // 4MB (dead after qk gemm)
    unsigned short* vwb  = (unsigned short*)(ws + 12 * MB);  // 2MB
    unsigned short* owb  = (unsigned short*)(ws + 14 * MB);  // 2MB
    unsigned short* w1b  = (unsigned short*)(ws + 16 * MB);  // 8MB
    unsigned short* w2b  = (unsigned short*)(ws + 24 * MB);  // 8MB
    unsigned short* Qbuf = (unsigned short*)(ws + 32 * MB);  // 8MB
    unsigned short* Kbuf = (unsigned short*)(ws + 40 * MB);  // 8MB
    unsigned short* Vtb  = (unsigned short*)(ws + 48 * MB);  // 8MB
    unsigned short* atto = (unsigned short*)(ws + 56 * MB);  // 8MB
    unsigned short* hbuf = (unsigned short*)(ws + 32 * MB);  // 32MB, reuses Q/K/V/atto after attn
    float* y1 = (float*)(ws + 64 * MB);                      // 16MB (after combine)
    unsigned short* Oprt = (unsigned short*)(ws + 64 * MB);  // 16MB partials (dead before y1)
    float* Mws = (float*)(ws + 8 * MB);                      // 512KB (reuses dead qkwb)
    float* Lws = (float*)(ws + 8 * MB + 512 * 1024);         // 512KB

    // fused weight converts (single launch: qk_w | v_w | out_w | w1 | w2)
    cvt5_kernel<<<12288, 256, 0, stream>>>(qk_w, qkwb, v_w, vwb, out_w, owb,
                                           w1, w1b, w2, w2b);

    // LN1
    ln_kernel<<<4096, 256, 0, stream>>>(x, ln_w, ln_b, xn);

    // qk projection + mixing
    {
        dim3 g(2048 / 128, 4096 / 128);   // 512 blocks
        gemm_bt<0><<<g, 256, 0, stream>>>(xn, qkwb, qk_b, 4096, 2048, 1024,
                                          Qin, Kin, Qout, Kout, Qbuf, Kbuf);
    }
    // v projection + mixing (+ transposed bf16 copy)
    {
        dim3 g(1024 / 128, 4096 / 128);   // 256 blocks
        gemm_bt<1><<<g, 256, 0, stream>>>(xn, vwb, v_b, 4096, 1024, 1024,
                                          Vin, nullptr, Vout, nullptr, Vtb, nullptr);
    }
    // attention (split-KV x2) + combine
    {
        dim3 g(16, 64, 2);
        attn_kernel<<<g, 256, 0, stream>>>(Qbuf, Kbuf, Vtb, Oprt, Mws, Lws);
        attn_combine<<<4096, 256, 0, stream>>>(Oprt, Mws, Lws, atto);
    }
    // out projection + residual -> y1
    {
        dim3 g(1024 / 128, 4096 / 128);   // 256 blocks
        gemm_bt<2><<<g, 256, 0, stream>>>(atto, owb, out_b, 4096, 1024, 1024,
                                          x, nullptr, y1, nullptr, nullptr, nullptr);
    }
    // LN2
    ln_kernel<<<4096, 256, 0, stream>>>(y1, ln_w, ln_b, xn);
    // MLP fc1 + GELU: pipelined 256x256 big kernel (256 blocks, 512 threads)
    {
        dim3 g(4096 / 256, 4096 / 256);
        gemm_big_gelu<<<g, 512, 0, stream>>>(xn, w1b, b1, 4096, 4096, 1024, hbuf);
    }
    // MLP fc2 + residual -> out0 (verified 128^2 path)
    {
        dim3 g(1024 / 128, 4096 / 128);   // 256 blocks
        gemm_bt<2><<<g, 256, 0, stream>>>(hbuf, w2b, b2, 4096, 1024, 4096,
                                          y1, nullptr, out0, nullptr, nullptr, nullptr);
    }
}

// Round 24
// 253.277 us; speedup vs baseline: 1.0237x; 1.0237x over previous
//
#include <hip/hip_runtime.h>

// ---------------------------------------------------------------------------
// Types
// ---------------------------------------------------------------------------
using bf16x8 = __attribute__((ext_vector_type(8))) __bf16;
using f32x4  = __attribute__((ext_vector_type(4))) float;

#define AS1(p) (const __attribute__((address_space(1))) void*)(p)
#define AS3(p) (__attribute__((address_space(3))) void*)(p)

__device__ __forceinline__ unsigned short f2bf(float f) {
    unsigned int u = __float_as_uint(f);
    unsigned int r = (u + 0x7FFFu + ((u >> 16) & 1u)) >> 16;
    return (unsigned short)r;
}
__device__ __forceinline__ float bf2f(unsigned short u) {
    return __uint_as_float((unsigned int)u << 16);
}
// tanh-form GELU: x*sigmoid(1.5957691*(x+0.044715x^3)); |err vs erf-GELU|<4e-4
__device__ __forceinline__ float gelu_fast(float x) {
    const float a = 1.5957691f * (x + 0.044715f * x * x * x);
    return x / (1.0f + __expf(-a));
}

// ---------------------------------------------------------------------------
// Fused fp32 -> bf16 convert for all 5 weight tensors (single launch).
// Segments (in 1024-elem blocks): qk_w 2048 | v_w 1024 | out_w 1024 |
// w1 4096 | w2 4096  -> 12288 blocks total. Branch is block-uniform.
// ---------------------------------------------------------------------------
__global__ __launch_bounds__(256)
void cvt5_kernel(const float* __restrict__ s0, unsigned short* __restrict__ d0,
                 const float* __restrict__ s1, unsigned short* __restrict__ d1,
                 const float* __restrict__ s2, unsigned short* __restrict__ d2,
                 const float* __restrict__ s3, unsigned short* __restrict__ d3,
                 const float* __restrict__ s4, unsigned short* __restrict__ d4) {
    const int b = blockIdx.x;
    const float* s; unsigned short* d; int base;
    if (b < 2048)      { s = s0; d = d0; base = 0; }
    else if (b < 3072) { s = s1; d = d1; base = 2048; }
    else if (b < 4096) { s = s2; d = d2; base = 3072; }
    else if (b < 8192) { s = s3; d = d3; base = 4096; }
    else               { s = s4; d = d4; base = 8192; }
    const int i = (b - base) * 1024 + threadIdx.x * 4;
    const float4 v = *(const float4*)(s + i);
    *(ushort4*)(d + i) = make_ushort4(f2bf(v.x), f2bf(v.y), f2bf(v.z), f2bf(v.w));
}

// ---------------------------------------------------------------------------
// LayerNorm: one 1024-wide row per block (256 threads x 4 elems), bf16 out
// ---------------------------------------------------------------------------
__global__ __launch_bounds__(256) void ln_kernel(const float* __restrict__ in,
                                                 const float* __restrict__ w,
                                                 const float* __restrict__ b,
                                                 unsigned short* __restrict__ out) {
    const int row = blockIdx.x;
    const int tid = threadIdx.x;
    const float4 v = *(const float4*)(in + (size_t)row * 1024 + tid * 4);
    float s  = v.x + v.y + v.z + v.w;
    float ss = v.x * v.x + v.y * v.y + v.z * v.z + v.w * v.w;
    #pragma unroll
    for (int m = 1; m < 64; m <<= 1) {
        s  += __shfl_xor(s, m, 64);
        ss += __shfl_xor(ss, m, 64);
    }
    __shared__ float red[8];
    if ((tid & 63) == 0) { red[(tid >> 6) * 2] = s; red[(tid >> 6) * 2 + 1] = ss; }
    __syncthreads();
    s  = red[0] + red[2] + red[4] + red[6];
    ss = red[1] + red[3] + red[5] + red[7];
    const float mu  = s * (1.0f / 1024.0f);
    const float var = ss * (1.0f / 1024.0f) - mu * mu;
    const float rstd = rsqrtf(var + 1e-5f);
    const float4 wv = *(const float4*)(w + tid * 4);
    const float4 bv = *(const float4*)(b + tid * 4);
    ushort4 o;
    o.x = f2bf((v.x - mu) * rstd * wv.x + bv.x);
    o.y = f2bf((v.y - mu) * rstd * wv.y + bv.y);
    o.z = f2bf((v.z - mu) * rstd * wv.z + bv.z);
    o.w = f2bf((v.w - mu) * rstd * wv.w + bv.w);
    *(ushort4*)(out + (size_t)row * 1024 + tid * 4) = o;
}

// ---------------------------------------------------------------------------
// GEMM (128x128 tile, round-10/11 verified): 4 waves, BK=128, single-buffer
// 2-barrier loop, 16-slot XOR swizzle, T1 XCD-chunked block swizzle.
// EPI: 0=QK mix, 1=V mix+transpose, 2=(out-proj|mlp2)+resid
// ---------------------------------------------------------------------------
template <int EPI>
__global__ __launch_bounds__(256, 2)
void gemm_bt(const unsigned short* __restrict__ A,
             const unsigned short* __restrict__ W,
             const float* __restrict__ bias,
             int M, int N, int K,
             const float* __restrict__ e0, const float* __restrict__ e1,
             float* __restrict__ o0, float* __restrict__ o1,
             unsigned short* __restrict__ u0, unsigned short* __restrict__ u1) {
    __shared__ unsigned short As[128 * 128];   // 32KB, [row][128 elems=256B]
    __shared__ unsigned short Bs[128 * 128];   // 32KB
    const int tid  = threadIdx.x;
    const int wave = tid >> 6, lane = tid & 63;
    const int wr = wave >> 1, wc = wave & 1;
    const int q15 = lane & 15, g = lane >> 4;

    const int gx = gridDim.x;
    const int nwg = gx * gridDim.y;
    int flat = blockIdx.y * gx + blockIdx.x;
    flat = (flat & 7) * (nwg >> 3) + (flat >> 3);
    const int gm0 = (flat / gx) * 128, gn0 = (flat % gx) * 128;

    f32x4 acc[4][4] = {};

    const int lrow4 = lane >> 4;            // 0..3 row within instr
    const int lslot = lane & 15;            // 16B slot within 256B row
    const int rswz  = q15 << 4;             // read-side XOR bytes ((row&15)<<4)

    for (int k0 = 0; k0 < K; k0 += 128) {
        #pragma unroll
        for (int i = 0; i < 8; ++i) {
            const int row  = wave * 32 + i * 4 + lrow4;
            const int selm = (lslot ^ (row & 15)) << 3;   // element offset
            __builtin_amdgcn_global_load_lds(AS1(A + (size_t)(gm0 + row) * K + k0 + selm),
                                             AS3((char*)As + wave * 8192 + i * 1024), 16, 0, 0);
            __builtin_amdgcn_global_load_lds(AS1(W + (size_t)(gn0 + row) * K + k0 + selm),
                                             AS3((char*)Bs + wave * 8192 + i * 1024), 16, 0, 0);
        }
        __syncthreads();
        #pragma unroll
        for (int kk = 0; kk < 4; ++kk) {
            bf16x8 af[4], bfr[4];
            #pragma unroll
            for (int m = 0; m < 4; ++m)
                af[m] = *(const bf16x8*)((char*)As + (wr * 64 + m * 16 + q15) * 256 +
                                         ((kk * 64 + g * 16) ^ rswz));
            #pragma unroll
            for (int n = 0; n < 4; ++n)
                bfr[n] = *(const bf16x8*)((char*)Bs + (wc * 64 + n * 16 + q15) * 256 +
                                          ((kk * 64 + g * 16) ^ rswz));
            #pragma unroll
            for (int m = 0; m < 4; ++m)
                #pragma unroll
                for (int n = 0; n < 4; ++n)
                    acc[m][n] = __builtin_amdgcn_mfma_f32_16x16x32_bf16(af[m], bfr[n], acc[m][n], 0, 0, 0);
        }
        __syncthreads();
    }

    #pragma unroll
    for (int m = 0; m < 4; ++m)
    #pragma unroll
    for (int n = 0; n < 4; ++n)
    #pragma unroll
    for (int j = 0; j < 4; ++j) {
        const int r = gm0 + wr * 64 + m * 16 + g * 4 + j;
        const int c = gn0 + wc * 64 + n * 16 + q15;
        const float val = acc[m][n][j] + bias[c];
        if constexpr (EPI == 0) {            // qk: mix with Query/Key inputs
            const int bb = r >> 10, nn = r & 1023;
            const int h = c >> 7, hs = (c >> 1) & 63, isk = c & 1;
            const size_t idx = (((size_t)(bb * 16 + h)) * 1024 + nn) * 64 + hs;
            if (!isk) { const float mx = 0.7f * val + 0.3f * e0[idx]; o0[idx] = mx; u0[idx] = f2bf(mx); }
            else      { const float mx = 0.7f * val + 0.3f * e1[idx]; o1[idx] = mx; u1[idx] = f2bf(mx); }
        } else if constexpr (EPI == 1) {     // v: mix + write transposed bf16
            const int bb = r >> 10, nn = r & 1023;
            const int h = c >> 6, hs = c & 63;
            const size_t idx = (((size_t)(bb * 16 + h)) * 1024 + nn) * 64 + hs;
            const float mx = 0.7f * val + 0.3f * e0[idx];
            o0[idx] = mx;
            u0[(((size_t)(bb * 16 + h)) * 64 + hs) * 1024 + nn] = f2bf(mx);
        } else {                             // +residual -> fp32
            const size_t idx = (size_t)r * N + c;
            o0[idx] = val + e0[idx];
        }
    }
}

// ---------------------------------------------------------------------------
// PIPELINED BIG GEMM (mlp1): 256x256 tile, 8 waves (2Mx4N), BK=32,
// 3-RING LDS (96KB), counted vmcnt(4) + one s_barrier per K-tile
// (R14-verified schedule & swizzle).  Epilogue: GELU -> bf16.
// ---------------------------------------------------------------------------
__global__ __launch_bounds__(512, 1)
void gemm_big_gelu(const unsigned short* __restrict__ A,
                   const unsigned short* __restrict__ W,
                   const float* __restrict__ bias,
                   int M, int N, int K,
                   unsigned short* __restrict__ u0) {
    __shared__ unsigned short Ls[3][2][256 * 32];   // 96KB
    const int tid  = threadIdx.x;
    const int wave = tid >> 6, lane = tid & 63;
    const int wr = wave >> 2, wc = wave & 3;        // 2M x 4N
    const int q15 = lane & 15, g = lane >> 4;       // g = k-slot 0..3

    const int gx = gridDim.x;
    const int nwg = gx * gridDim.y;
    int flat = blockIdx.y * gx + blockIdx.x;
    flat = (flat & 7) * (nwg >> 3) + (flat >> 3);
    const int gm0 = (flat / gx) * 256, gn0 = (flat % gx) * 256;

    f32x4 acc[8][4] = {};

    const int srow  = tid >> 2;                        // 0..127
    const int sslot = (tid & 3) ^ ((srow >> 1) & 3);
    const int selm  = sslot << 3;                      // element offset

    #define STAGEH(kt, p, rb)                                                        \
        {                                                                            \
            const unsigned short* src_ = ((p) < 2) ? A : W;                          \
            const int gbase_ = ((p) < 2) ? gm0 : gn0;                                \
            const int row_ = ((p) & 1) * 128 + srow;                                 \
            __builtin_amdgcn_global_load_lds(                                        \
                AS1(src_ + (size_t)(gbase_ + row_) * K + (kt) * 32 + selm),          \
                AS3((char*)Ls[rb][(p) >> 1] + ((p) & 1) * 8192 + tid * 16),          \
                16, 0, 0);                                                           \
        }

    const int nt = K >> 5;
    #pragma unroll
    for (int p = 0; p < 4; ++p) STAGEH(0, p, 0);
    #pragma unroll
    for (int p = 0; p < 4; ++p) STAGEH(1, p, 1);

    int rb = 0;
    for (int t = 0; t < nt; ++t) {
        if (t >= nt - 1) { asm volatile("s_waitcnt vmcnt(0)" ::: "memory"); }
        else             { asm volatile("s_waitcnt vmcnt(4)" ::: "memory"); }
        asm volatile("s_barrier" ::: "memory");
        const int rb2 = (rb >= 1) ? rb - 1 : rb + 2;   // (rb+2)%3
        const char* Ab = (const char*)Ls[rb][0];
        const char* Bb = (const char*)Ls[rb][1];
        #pragma unroll
        for (int p = 0; p < 4; ++p) {                  // quadrant (mh,nh)
            if (t + 2 < nt) STAGEH(t + 2, p, rb2);
            const int mh = p >> 1, nh = p & 1;
            bf16x8 af[4], bf[2];
            #pragma unroll
            for (int mm = 0; mm < 4; ++mm) {
                const int row = wr * 128 + mh * 64 + mm * 16 + q15;
                af[mm] = *(const bf16x8*)(Ab + row * 64 + ((g ^ ((row >> 1) & 3)) << 4));
            }
            #pragma unroll
            for (int nn = 0; nn < 2; ++nn) {
                const int row = wc * 64 + nh * 32 + nn * 16 + q15;
                bf[nn] = *(const bf16x8*)(Bb + row * 64 + ((g ^ ((row >> 1) & 3)) << 4));
            }
            __builtin_amdgcn_s_setprio(1);
            #pragma unroll
            for (int mm = 0; mm < 4; ++mm)
                #pragma unroll
                for (int nn = 0; nn < 2; ++nn)
                    acc[mh * 4 + mm][nh * 2 + nn] = __builtin_amdgcn_mfma_f32_16x16x32_bf16(
                        af[mm], bf[nn], acc[mh * 4 + mm][nh * 2 + nn], 0, 0, 0);
            __builtin_amdgcn_s_setprio(0);
        }
        rb = (rb == 2) ? 0 : rb + 1;
    }
    #undef STAGEH

    #pragma unroll
    for (int m = 0; m < 8; ++m)
    #pragma unroll
    for (int n = 0; n < 4; ++n)
    #pragma unroll
    for (int j = 0; j < 4; ++j) {
        const int r = gm0 + wr * 128 + m * 16 + g * 4 + j;
        const int c = gn0 + wc * 64 + n * 16 + q15;
        const float val = acc[m][n][j] + bias[c];
        u0[(size_t)r * N + c] = f2bf(gelu_fast(val));
    }
}

// ---------------------------------------------------------------------------
// Flash attention, split-KV x2, LDS-staged K/V, swapped-QK^T in-reg softmax.
// grid (N/64, B*H, 2), 256 threads = 4 waves x 16 q-rows.  (round-5 verified)
// ---------------------------------------------------------------------------
__global__ __launch_bounds__(256, 6)
void attn_kernel(const unsigned short* __restrict__ Qb,
                 const unsigned short* __restrict__ Kb,
                 const unsigned short* __restrict__ Vt,
                 unsigned short* __restrict__ Op,   // [2][64][1024][64] bf16
                 float* __restrict__ Mws,           // [2][64][1024]
                 float* __restrict__ Lws) {         // [2][64][1024]
    const int bh = blockIdx.y;
    const int z  = blockIdx.z;
    const int tid = threadIdx.x, wave = tid >> 6, lane = tid & 63;
    const int qbase = blockIdx.x * 64 + wave * 16;
    const int q15 = lane & 15, g = lane >> 4;

    const unsigned short* Qh = Qb + (size_t)bh * 1024 * 64;
    const unsigned short* Kh = Kb + (size_t)bh * 1024 * 64;
    const unsigned short* Vh = Vt + (size_t)bh * 64 * 1024;

    __shared__ alignas(128) unsigned short Ks[64 * 64];   // 8KB
    __shared__ alignas(128) unsigned short Vs[64 * 64];   // 8KB
    __shared__ alignas(128) unsigned short Ps[4][1024];   // 8KB (2KB/wave)
    char* const Pb = (char*)Ps[wave] + q15 * 128;
    const int swz = (q15 & 7) << 4;

    const int srow8 = lane >> 3;                       // 0..7
    const int selm  = (((lane & 7) ^ srow8) << 3);     // pre-swizzled element

    bf16x8 aq[2];
    aq[0] = *(const bf16x8*)&Qh[(size_t)(qbase + q15) * 64 + 0  + g * 8];
    aq[1] = *(const bf16x8*)&Qh[(size_t)(qbase + q15) * 64 + 32 + g * 8];

    f32x4 o[4] = {};
    float mrow = -1e30f, lrow = 0.f;

    const int t0 = z * 8;
    for (int t = t0; t < t0 + 8; ++t) {
        const int kb = t * 64;
        #pragma unroll
        for (int i = 0; i < 2; ++i) {
            const int r = wave * 16 + i * 8 + srow8;
            __builtin_amdgcn_global_load_lds(AS1(Kh + (size_t)(kb + r) * 64 + selm),
                                             AS3((char*)Ks + wave * 2048 + i * 1024), 16, 0, 0);
            __builtin_amdgcn_global_load_lds(AS1(Vh + (size_t)r * 1024 + kb + selm),
                                             AS3((char*)Vs + wave * 2048 + i * 1024), 16, 0, 0);
        }
        __syncthreads();

        f32x4 s[4] = {};
        #pragma unroll
        for (int kt = 0; kt < 4; ++kt) {
            #pragma unroll
            for (int kk = 0; kk < 2; ++kk) {
                const bf16x8 bk = *(const bf16x8*)((char*)Ks + (kt * 16 + q15) * 128 +
                                                   ((kk * 64 + g * 16) ^ swz));
                s[kt] = __builtin_amdgcn_mfma_f32_16x16x32_bf16(bk, aq[kk], s[kt], 0, 0, 0);
            }
        }
        float pm = -1e30f;
        #pragma unroll
        for (int kt = 0; kt < 4; ++kt) {
            s[kt] *= 0.125f;
            pm = fmaxf(pm, fmaxf(fmaxf(s[kt][0], s[kt][1]), fmaxf(s[kt][2], s[kt][3])));
        }
        pm = fmaxf(pm, __shfl_xor(pm, 16, 64));
        pm = fmaxf(pm, __shfl_xor(pm, 32, 64));
        const float mnew = fmaxf(mrow, pm);
        const float alpha = __expf(mrow - mnew);
        mrow = mnew;

        float rs = 0.f;
        #pragma unroll
        for (int kt = 0; kt < 4; ++kt) {
            const float p0 = __expf(s[kt][0] - mnew);
            const float p1 = __expf(s[kt][1] - mnew);
            const float p2 = __expf(s[kt][2] - mnew);
            const float p3 = __expf(s[kt][3] - mnew);
            rs += (p0 + p1) + (p2 + p3);
            uint2 pk;
            pk.x = (unsigned int)f2bf(p0) | ((unsigned int)f2bf(p1) << 16);
            pk.y = (unsigned int)f2bf(p2) | ((unsigned int)f2bf(p3) << 16);
            *(uint2*)(Pb + (((kt * 32 + g * 8) ^ swz))) = pk;
        }
        rs += __shfl_xor(rs, 16, 64);
        rs += __shfl_xor(rs, 32, 64);
        lrow = lrow * alpha + rs;

        float af[4];
        #pragma unroll
        for (int j = 0; j < 4; ++j) af[j] = __shfl(alpha, g * 4 + j, 64);
        #pragma unroll
        for (int dt = 0; dt < 4; ++dt)
            #pragma unroll
            for (int j = 0; j < 4; ++j) o[dt][j] *= af[j];

        #pragma unroll
        for (int Bb = 0; Bb < 2; ++Bb) {
            const bf16x8 pa = *(const bf16x8*)(Pb + (((Bb * 64 + g * 16) ^ swz)));
            #pragma unroll
            for (int dt = 0; dt < 4; ++dt) {
                const bf16x8 vb = *(const bf16x8*)((char*)Vs + (dt * 16 + q15) * 128 +
                                                   ((Bb * 64 + g * 16) ^ swz));
                o[dt] = __builtin_amdgcn_mfma_f32_16x16x32_bf16(pa, vb, o[dt], 0, 0, 0);
            }
        }
        __syncthreads();
    }

    #pragma unroll
    for (int dt = 0; dt < 4; ++dt)
        #pragma unroll
        for (int j = 0; j < 4; ++j) {
            const int q = qbase + g * 4 + j;
            Op[(((size_t)z * 64 + bh) * 1024 + q) * 64 + dt * 16 + q15] = f2bf(o[dt][j]);
        }
    if (g == 0) {
        const size_t mi = ((size_t)z * 64 + bh) * 1024 + qbase + q15;
        Mws[mi] = mrow;
        Lws[mi] = lrow;
    }
}

// ---------------------------------------------------------------------------
// Combine the two kv-halves
// ---------------------------------------------------------------------------
__global__ __launch_bounds__(256)
void attn_combine(const unsigned short* __restrict__ Op,
                  const float* __restrict__ Mws,
                  const float* __restrict__ Lws,
                  unsigned short* __restrict__ Ob) {
    const int e4 = blockIdx.x * 256 + threadIdx.x;
    const int d0 = (e4 & 15) * 4;
    const int q  = (e4 >> 4) & 1023;
    const int bh = e4 >> 14;
    const size_t base0 = (((size_t)bh) * 1024 + q) * 64 + d0;
    const size_t base1 = (((size_t)(64 + bh)) * 1024 + q) * 64 + d0;
    const ushort4 a = *(const ushort4*)&Op[base0];
    const ushort4 c = *(const ushort4*)&Op[base1];
    const size_t mi0 = (size_t)bh * 1024 + q;
    const size_t mi1 = mi0 + 64 * 1024;
    const float m0 = Mws[mi0], m1 = Mws[mi1];
    const float l0 = Lws[mi0], l1 = Lws[mi1];
    const float m  = fmaxf(m0, m1);
    const float w0 = __expf(m0 - m), w1 = __expf(m1 - m);
    const float inv = 1.0f / (l0 * w0 + l1 * w1);
    ushort4 r;
    r.x = f2bf((bf2f(a.x) * w0 + bf2f(c.x) * w1) * inv);
    r.y = f2bf((bf2f(a.y) * w0 + bf2f(c.y) * w1) * inv);
    r.z = f2bf((bf2f(a.z) * w0 + bf2f(c.z) * w1) * inv);
    r.w = f2bf((bf2f(a.w) * w0 + bf2f(c.w) * w1) * inv);
    const int b = bh >> 4, h = bh & 15;
    *(ushort4*)&Ob[((size_t)(b * 1024 + q)) * 1024 + h * 64 + d0] = r;
}

// ---------------------------------------------------------------------------
// Launch  (final: R20/R22 best-known configuration, 253.0 us)
// ---------------------------------------------------------------------------
extern "C" void kernel_launch(void* const* d_in, const int* in_sizes, int n_in,
                              void* d_out, int out_size, void* d_ws, size_t ws_size,
                              hipStream_t stream) {
    (void)in_sizes; (void)n_in; (void)out_size; (void)ws_size;
    const float* x     = (const float*)d_in[0];
    const float* Qin   = (const float*)d_in[1];
    const float* Kin   = (const float*)d_in[2];
    const float* Vin   = (const float*)d_in[3];
    const float* ln_w  = (const float*)d_in[4];
    const float* ln_b  = (const float*)d_in[5];
    const float* qk_w  = (const float*)d_in[6];
    const float* qk_b  = (const float*)d_in[7];
    const float* v_w   = (const float*)d_in[8];
    const float* v_b   = (const float*)d_in[9];
    const float* out_w = (const float*)d_in[10];
    const float* out_b = (const float*)d_in[11];
    const float* w1    = (const float*)d_in[12];
    const float* b1    = (const float*)d_in[13];
    const float* w2    = (const float*)d_in[14];
    const float* b2    = (const float*)d_in[15];

    const size_t FOUR_M = (size_t)4 * 1024 * 1024;
    float* out0 = (float*)d_out;
    float* Qout = out0 + FOUR_M;
    float* Kout = Qout + FOUR_M;
    float* Vout = Kout + FOUR_M;

    char* ws = (char*)d_ws;
    const size_t MB = 1024 * 1024;
    unsigned short* xn   = (unsigned short*)(ws + 0);        // 8MB (reused as xn2)
    unsigned short* qkwb = (unsigned short*)(ws + 8 * MB);   // 4MB (dead after qk gemm)
    unsigned short* vwb  = (unsigned short*)(ws + 12 * MB);  // 2MB
    unsigned short* owb  = (unsigned short*)(ws + 14 * MB);  // 2MB
    unsigned short* w1b  = (unsigned short*)(ws + 16 * MB);  // 8MB
    unsigned short* w2b  = (unsigned short*)(ws + 24 * MB);  // 8MB
    unsigned short* Qbuf = (unsigned short*)(ws + 32 * MB);  // 8MB
    unsigned short* Kbuf = (unsigned short*)(ws + 40 * MB);  // 8MB
    unsigned short* Vtb  = (unsigned short*)(ws + 48 * MB);  // 8MB
    unsigned short* atto = (unsigned short*)(ws + 56 * MB);  // 8MB
    unsigned short* hbuf = (unsigned short*)(ws + 32 * MB);  // 32MB, reuses Q/K/V/atto after attn
    float* y1 = (float*)(ws + 64 * MB);                      // 16MB (after combine)
    unsigned short* Oprt = (unsigned short*)(ws + 64 * MB);  // 16MB partials (dead before y1)
    float* Mws = (float*)(ws + 8 * MB);                      // 512KB (reuses dead qkwb)
    float* Lws = (float*)(ws + 8 * MB + 512 * 1024);         // 512KB

    // fused weight converts (single launch: qk_w | v_w | out_w | w1 | w2)
    cvt5_kernel<<<12288, 256, 0, stream>>>(qk_w, qkwb, v_w, vwb, out_w, owb,
                                           w1, w1b, w2, w2b);

    // LN1
    ln_kernel<<<4096, 256, 0, stream>>>(x, ln_w, ln_b, xn);

    // qk projection + mixing
    {
        dim3 g(2048 / 128, 4096 / 128);   // 512 blocks
        gemm_bt<0><<<g, 256, 0, stream>>>(xn, qkwb, qk_b, 4096, 2048, 1024,
                                          Qin, Kin, Qout, Kout, Qbuf, Kbuf);
    }
    // v projection + mixing (+ transposed bf16 copy)
    {
        dim3 g(1024 / 128, 4096 / 128);   // 256 blocks
        gemm_bt<1><<<g, 256, 0, stream>>>(xn, vwb, v_b, 4096, 1024, 1024,
                                          Vin, nullptr, Vout, nullptr, Vtb, nullptr);
    }
    // attention (split-KV x2) + combine
    {
        dim3 g(16, 64, 2);
        attn_kernel<<<g, 256, 0, stream>>>(Qbuf, Kbuf, Vtb, Oprt, Mws, Lws);
        attn_combine<<<4096, 256, 0, stream>>>(Oprt, Mws, Lws, atto);
    }
    // out projection + residual -> y1
    {
        dim3 g(1024 / 128, 4096 / 128);   // 256 blocks
        gemm_bt<2><<<g, 256, 0, stream>>>(atto, owb, out_b, 4096, 1024, 1024,
                                          x, nullptr, y1, nullptr, nullptr, nullptr);
    }
    // LN2
    ln_kernel<<<4096, 256, 0, stream>>>(y1, ln_w, ln_b, xn);
    // MLP fc1 + GELU: pipelined 256x256 big kernel (256 blocks, 512 threads)
    {
        dim3 g(4096 / 256, 4096 / 256);
        gemm_big_gelu<<<g, 512, 0, stream>>>(xn, w1b, b1, 4096, 4096, 1024, hbuf);
    }
    // MLP fc2 + residual -> out0 (verified 128^2 path)
    {
        dim3 g(1024 / 128, 4096 / 128);   // 256 blocks
        gemm_bt<2><<<g, 256, 0, stream>>>(hbuf, w2b, b2, 4096, 1024, 4096,
                                          y1, nullptr, out0, nullptr, nullptr, nullptr);
    }
}

// Round 25
// 245.428 us; speedup vs baseline: 1.0564x; 1.0320x over previous
//
#include <hip/hip_runtime.h>

// ---------------------------------------------------------------------------
// Types
// ---------------------------------------------------------------------------
using bf16x8 = __attribute__((ext_vector_type(8))) __bf16;
using f32x4  = __attribute__((ext_vector_type(4))) float;

#define AS1(p) (const __attribute__((address_space(1))) void*)(p)
#define AS3(p) (__attribute__((address_space(3))) void*)(p)

__device__ __forceinline__ unsigned short f2bf(float f) {
    unsigned int u = __float_as_uint(f);
    unsigned int r = (u + 0x7FFFu + ((u >> 16) & 1u)) >> 16;
    return (unsigned short)r;
}
__device__ __forceinline__ float bf2f(unsigned short u) {
    return __uint_as_float((unsigned int)u << 16);
}
// tanh-form GELU: x*sigmoid(1.5957691*(x+0.044715x^3)); |err vs erf-GELU|<4e-4
__device__ __forceinline__ float gelu_fast(float x) {
    const float a = 1.5957691f * (x + 0.044715f * x * x * x);
    return x / (1.0f + __expf(-a));
}

// ---------------------------------------------------------------------------
// Fused fp32 -> bf16 convert for all 5 weight tensors (single launch).
// Segments (in 1024-elem blocks): qk_w 2048 | v_w 1024 | out_w 1024 |
// w1 4096 | w2 4096  -> 12288 blocks total. Branch is block-uniform.
// ---------------------------------------------------------------------------
__global__ __launch_bounds__(256)
void cvt5_kernel(const float* __restrict__ s0, unsigned short* __restrict__ d0,
                 const float* __restrict__ s1, unsigned short* __restrict__ d1,
                 const float* __restrict__ s2, unsigned short* __restrict__ d2,
                 const float* __restrict__ s3, unsigned short* __restrict__ d3,
                 const float* __restrict__ s4, unsigned short* __restrict__ d4) {
    const int b = blockIdx.x;
    const float* s; unsigned short* d; int base;
    if (b < 2048)      { s = s0; d = d0; base = 0; }
    else if (b < 3072) { s = s1; d = d1; base = 2048; }
    else if (b < 4096) { s = s2; d = d2; base = 3072; }
    else if (b < 8192) { s = s3; d = d3; base = 4096; }
    else               { s = s4; d = d4; base = 8192; }
    const int i = (b - base) * 1024 + threadIdx.x * 4;
    const float4 v = *(const float4*)(s + i);
    *(ushort4*)(d + i) = make_ushort4(f2bf(v.x), f2bf(v.y), f2bf(v.z), f2bf(v.w));
}

// ---------------------------------------------------------------------------
// LayerNorm: one 1024-wide row per block (256 threads x 4 elems), bf16 out
// ---------------------------------------------------------------------------
__global__ __launch_bounds__(256) void ln_kernel(const float* __restrict__ in,
                                                 const float* __restrict__ w,
                                                 const float* __restrict__ b,
                                                 unsigned short* __restrict__ out) {
    const int row = blockIdx.x;
    const int tid = threadIdx.x;
    const float4 v = *(const float4*)(in + (size_t)row * 1024 + tid * 4);
    float s  = v.x + v.y + v.z + v.w;
    float ss = v.x * v.x + v.y * v.y + v.z * v.z + v.w * v.w;
    #pragma unroll
    for (int m = 1; m < 64; m <<= 1) {
        s  += __shfl_xor(s, m, 64);
        ss += __shfl_xor(ss, m, 64);
    }
    __shared__ float red[8];
    if ((tid & 63) == 0) { red[(tid >> 6) * 2] = s; red[(tid >> 6) * 2 + 1] = ss; }
    __syncthreads();
    s  = red[0] + red[2] + red[4] + red[6];
    ss = red[1] + red[3] + red[5] + red[7];
    const float mu  = s * (1.0f / 1024.0f);
    const float var = ss * (1.0f / 1024.0f) - mu * mu;
    const float rstd = rsqrtf(var + 1e-5f);
    const float4 wv = *(const float4*)(w + tid * 4);
    const float4 bv = *(const float4*)(b + tid * 4);
    ushort4 o;
    o.x = f2bf((v.x - mu) * rstd * wv.x + bv.x);
    o.y = f2bf((v.y - mu) * rstd * wv.y + bv.y);
    o.z = f2bf((v.z - mu) * rstd * wv.z + bv.z);
    o.w = f2bf((v.w - mu) * rstd * wv.w + bv.w);
    *(ushort4*)(out + (size_t)row * 1024 + tid * 4) = o;
}

// ---------------------------------------------------------------------------
// GEMM (128x128 tile, round-10/11 verified): 4 waves, BK=128, single-buffer
// 2-barrier loop, 16-slot XOR swizzle, T1 XCD-chunked block swizzle.
// EPI: 0=QK mix, 1=V mix+transpose, 2=(out-proj|mlp2)+resid
// ---------------------------------------------------------------------------
template <int EPI>
__global__ __launch_bounds__(256, 2)
void gemm_bt(const unsigned short* __restrict__ A,
             const unsigned short* __restrict__ W,
             const float* __restrict__ bias,
             int M, int N, int K,
             const float* __restrict__ e0, const float* __restrict__ e1,
             float* __restrict__ o0, float* __restrict__ o1,
             unsigned short* __restrict__ u0, unsigned short* __restrict__ u1) {
    __shared__ unsigned short As[128 * 128];   // 32KB, [row][128 elems=256B]
    __shared__ unsigned short Bs[128 * 128];   // 32KB
    const int tid  = threadIdx.x;
    const int wave = tid >> 6, lane = tid & 63;
    const int wr = wave >> 1, wc = wave & 1;
    const int q15 = lane & 15, g = lane >> 4;

    const int gx = gridDim.x;
    const int nwg = gx * gridDim.y;
    int flat = blockIdx.y * gx + blockIdx.x;
    flat = (flat & 7) * (nwg >> 3) + (flat >> 3);
    const int gm0 = (flat / gx) * 128, gn0 = (flat % gx) * 128;

    f32x4 acc[4][4] = {};

    const int lrow4 = lane >> 4;            // 0..3 row within instr
    const int lslot = lane & 15;            // 16B slot within 256B row
    const int rswz  = q15 << 4;             // read-side XOR bytes ((row&15)<<4)

    for (int k0 = 0; k0 < K; k0 += 128) {
        #pragma unroll
        for (int i = 0; i < 8; ++i) {
            const int row  = wave * 32 + i * 4 + lrow4;
            const int selm = (lslot ^ (row & 15)) << 3;   // element offset
            __builtin_amdgcn_global_load_lds(AS1(A + (size_t)(gm0 + row) * K + k0 + selm),
                                             AS3((char*)As + wave * 8192 + i * 1024), 16, 0, 0);
            __builtin_amdgcn_global_load_lds(AS1(W + (size_t)(gn0 + row) * K + k0 + selm),
                                             AS3((char*)Bs + wave * 8192 + i * 1024), 16, 0, 0);
        }
        __syncthreads();
        #pragma unroll
        for (int kk = 0; kk < 4; ++kk) {
            bf16x8 af[4], bfr[4];
            #pragma unroll
            for (int m = 0; m < 4; ++m)
                af[m] = *(const bf16x8*)((char*)As + (wr * 64 + m * 16 + q15) * 256 +
                                         ((kk * 64 + g * 16) ^ rswz));
            #pragma unroll
            for (int n = 0; n < 4; ++n)
                bfr[n] = *(const bf16x8*)((char*)Bs + (wc * 64 + n * 16 + q15) * 256 +
                                          ((kk * 64 + g * 16) ^ rswz));
            #pragma unroll
            for (int m = 0; m < 4; ++m)
                #pragma unroll
                for (int n = 0; n < 4; ++n)
                    acc[m][n] = __builtin_amdgcn_mfma_f32_16x16x32_bf16(af[m], bfr[n], acc[m][n], 0, 0, 0);
        }
        __syncthreads();
    }

    #pragma unroll
    for (int m = 0; m < 4; ++m)
    #pragma unroll
    for (int n = 0; n < 4; ++n)
    #pragma unroll
    for (int j = 0; j < 4; ++j) {
        const int r = gm0 + wr * 64 + m * 16 + g * 4 + j;
        const int c = gn0 + wc * 64 + n * 16 + q15;
        const float val = acc[m][n][j] + bias[c];
        if constexpr (EPI == 0) {            // qk: mix with Query/Key inputs
            const int bb = r >> 10, nn = r & 1023;
            const int h = c >> 7, hs = (c >> 1) & 63, isk = c & 1;
            const size_t idx = (((size_t)(bb * 16 + h)) * 1024 + nn) * 64 + hs;
            if (!isk) { const float mx = 0.7f * val + 0.3f * e0[idx]; o0[idx] = mx; u0[idx] = f2bf(mx); }
            else      { const float mx = 0.7f * val + 0.3f * e1[idx]; o1[idx] = mx; u1[idx] = f2bf(mx); }
        } else if constexpr (EPI == 1) {     // v: mix + write transposed bf16
            const int bb = r >> 10, nn = r & 1023;
            const int h = c >> 6, hs = c & 63;
            const size_t idx = (((size_t)(bb * 16 + h)) * 1024 + nn) * 64 + hs;
            const float mx = 0.7f * val + 0.3f * e0[idx];
            o0[idx] = mx;
            u0[(((size_t)(bb * 16 + h)) * 64 + hs) * 1024 + nn] = f2bf(mx);
        } else {                             // +residual -> fp32
            const size_t idx = (size_t)r * N + c;
            o0[idx] = val + e0[idx];
        }
    }
}

// ---------------------------------------------------------------------------
// PIPELINED BIG GEMM (mlp1): 256x256 tile, 8 waves (2Mx4N), BK=32,
// 3-RING LDS (96KB), counted vmcnt(4) + one s_barrier per K-tile
// (R14-verified schedule & swizzle).  Epilogue: GELU -> bf16.
// ---------------------------------------------------------------------------
__global__ __launch_bounds__(512, 1)
void gemm_big_gelu(const unsigned short* __restrict__ A,
                   const unsigned short* __restrict__ W,
                   const float* __restrict__ bias,
                   int M, int N, int K,
                   unsigned short* __restrict__ u0) {
    __shared__ unsigned short Ls[3][2][256 * 32];   // 96KB
    const int tid  = threadIdx.x;
    const int wave = tid >> 6, lane = tid & 63;
    const int wr = wave >> 2, wc = wave & 3;        // 2M x 4N
    const int q15 = lane & 15, g = lane >> 4;       // g = k-slot 0..3

    const int gx = gridDim.x;
    const int nwg = gx * gridDim.y;
    int flat = blockIdx.y * gx + blockIdx.x;
    flat = (flat & 7) * (nwg >> 3) + (flat >> 3);
    const int gm0 = (flat / gx) * 256, gn0 = (flat % gx) * 256;

    f32x4 acc[8][4] = {};

    const int srow  = tid >> 2;                        // 0..127
    const int sslot = (tid & 3) ^ ((srow >> 1) & 3);
    const int selm  = sslot << 3;                      // element offset

    #define STAGEH(kt, p, rb)                                                        \
        {                                                                            \
            const unsigned short* src_ = ((p) < 2) ? A : W;                          \
            const int gbase_ = ((p) < 2) ? gm0 : gn0;                                \
            const int row_ = ((p) & 1) * 128 + srow;                                 \
            __builtin_amdgcn_global_load_lds(                                        \
                AS1(src_ + (size_t)(gbase_ + row_) * K + (kt) * 32 + selm),          \
                AS3((char*)Ls[rb][(p) >> 1] + ((p) & 1) * 8192 + tid * 16),          \
                16, 0, 0);                                                           \
        }

    const int nt = K >> 5;
    #pragma unroll
    for (int p = 0; p < 4; ++p) STAGEH(0, p, 0);
    #pragma unroll
    for (int p = 0; p < 4; ++p) STAGEH(1, p, 1);

    int rb = 0;
    for (int t = 0; t < nt; ++t) {
        if (t >= nt - 1) { asm volatile("s_waitcnt vmcnt(0)" ::: "memory"); }
        else             { asm volatile("s_waitcnt vmcnt(4)" ::: "memory"); }
        asm volatile("s_barrier" ::: "memory");
        const int rb2 = (rb >= 1) ? rb - 1 : rb + 2;   // (rb+2)%3
        const char* Ab = (const char*)Ls[rb][0];
        const char* Bb = (const char*)Ls[rb][1];
        #pragma unroll
        for (int p = 0; p < 4; ++p) {                  // quadrant (mh,nh)
            if (t + 2 < nt) STAGEH(t + 2, p, rb2);
            const int mh = p >> 1, nh = p & 1;
            bf16x8 af[4], bf[2];
            #pragma unroll
            for (int mm = 0; mm < 4; ++mm) {
                const int row = wr * 128 + mh * 64 + mm * 16 + q15;
                af[mm] = *(const bf16x8*)(Ab + row * 64 + ((g ^ ((row >> 1) & 3)) << 4));
            }
            #pragma unroll
            for (int nn = 0; nn < 2; ++nn) {
                const int row = wc * 64 + nh * 32 + nn * 16 + q15;
                bf[nn] = *(const bf16x8*)(Bb + row * 64 + ((g ^ ((row >> 1) & 3)) << 4));
            }
            __builtin_amdgcn_s_setprio(1);
            #pragma unroll
            for (int mm = 0; mm < 4; ++mm)
                #pragma unroll
                for (int nn = 0; nn < 2; ++nn)
                    acc[mh * 4 + mm][nh * 2 + nn] = __builtin_amdgcn_mfma_f32_16x16x32_bf16(
                        af[mm], bf[nn], acc[mh * 4 + mm][nh * 2 + nn], 0, 0, 0);
            __builtin_amdgcn_s_setprio(0);
        }
        rb = (rb == 2) ? 0 : rb + 1;
    }
    #undef STAGEH

    #pragma unroll
    for (int m = 0; m < 8; ++m)
    #pragma unroll
    for (int n = 0; n < 4; ++n)
    #pragma unroll
    for (int j = 0; j < 4; ++j) {
        const int r = gm0 + wr * 128 + m * 16 + g * 4 + j;
        const int c = gn0 + wc * 64 + n * 16 + q15;
        const float val = acc[m][n][j] + bias[c];
        u0[(size_t)r * N + c] = f2bf(gelu_fast(val));
    }
}

// ---------------------------------------------------------------------------
// Flash attention, split-KV x2, LDS-staged K/V, swapped-QK^T in-reg softmax.
// grid (N/64, B*H, 2), 256 threads = 4 waves x 16 q-rows.  (round-5 verified)
// ---------------------------------------------------------------------------
__global__ __launch_bounds__(256, 6)
void attn_kernel(const unsigned short* __restrict__ Qb,
                 const unsigned short* __restrict__ Kb,
                 const unsigned short* __restrict__ Vt,
                 unsigned short* __restrict__ Op,   // [2][64][1024][64] bf16
                 float* __restrict__ Mws,           // [2][64][1024]
                 float* __restrict__ Lws) {         // [2][64][1024]
    const int bh = blockIdx.y;
    const int z  = blockIdx.z;
    const int tid = threadIdx.x, wave = tid >> 6, lane = tid & 63;
    const int qbase = blockIdx.x * 64 + wave * 16;
    const int q15 = lane & 15, g = lane >> 4;

    const unsigned short* Qh = Qb + (size_t)bh * 1024 * 64;
    const unsigned short* Kh = Kb + (size_t)bh * 1024 * 64;
    const unsigned short* Vh = Vt + (size_t)bh * 64 * 1024;

    __shared__ alignas(128) unsigned short Ks[64 * 64];   // 8KB
    __shared__ alignas(128) unsigned short Vs[64 * 64];   // 8KB
    __shared__ alignas(128) unsigned short Ps[4][1024];   // 8KB (2KB/wave)
    char* const Pb = (char*)Ps[wave] + q15 * 128;
    const int swz = (q15 & 7) << 4;

    const int srow8 = lane >> 3;                       // 0..7
    const int selm  = (((lane & 7) ^ srow8) << 3);     // pre-swizzled element

    bf16x8 aq[2];
    aq[0] = *(const bf16x8*)&Qh[(size_t)(qbase + q15) * 64 + 0  + g * 8];
    aq[1] = *(const bf16x8*)&Qh[(size_t)(qbase + q15) * 64 + 32 + g * 8];

    f32x4 o[4] = {};
    float mrow = -1e30f, lrow = 0.f;

    const int t0 = z * 8;
    for (int t = t0; t < t0 + 8; ++t) {
        const int kb = t * 64;
        #pragma unroll
        for (int i = 0; i < 2; ++i) {
            const int r = wave * 16 + i * 8 + srow8;
            __builtin_amdgcn_global_load_lds(AS1(Kh + (size_t)(kb + r) * 64 + selm),
                                             AS3((char*)Ks + wave * 2048 + i * 1024), 16, 0, 0);
            __builtin_amdgcn_global_load_lds(AS1(Vh + (size_t)r * 1024 + kb + selm),
                                             AS3((char*)Vs + wave * 2048 + i * 1024), 16, 0, 0);
        }
        __syncthreads();

        f32x4 s[4] = {};
        #pragma unroll
        for (int kt = 0; kt < 4; ++kt) {
            #pragma unroll
            for (int kk = 0; kk < 2; ++kk) {
                const bf16x8 bk = *(const bf16x8*)((char*)Ks + (kt * 16 + q15) * 128 +
                                                   ((kk * 64 + g * 16) ^ swz));
                s[kt] = __builtin_amdgcn_mfma_f32_16x16x32_bf16(bk, aq[kk], s[kt], 0, 0, 0);
            }
        }
        float pm = -1e30f;
        #pragma unroll
        for (int kt = 0; kt < 4; ++kt) {
            s[kt] *= 0.125f;
            pm = fmaxf(pm, fmaxf(fmaxf(s[kt][0], s[kt][1]), fmaxf(s[kt][2], s[kt][3])));
        }
        pm = fmaxf(pm, __shfl_xor(pm, 16, 64));
        pm = fmaxf(pm, __shfl_xor(pm, 32, 64));
        const float mnew = fmaxf(mrow, pm);
        const float alpha = __expf(mrow - mnew);
        mrow = mnew;

        float rs = 0.f;
        #pragma unroll
        for (int kt = 0; kt < 4; ++kt) {
            const float p0 = __expf(s[kt][0] - mnew);
            const float p1 = __expf(s[kt][1] - mnew);
            const float p2 = __expf(s[kt][2] - mnew);
            const float p3 = __expf(s[kt][3] - mnew);
            rs += (p0 + p1) + (p2 + p3);
            uint2 pk;
            pk.x = (unsigned int)f2bf(p0) | ((unsigned int)f2bf(p1) << 16);
            pk.y = (unsigned int)f2bf(p2) | ((unsigned int)f2bf(p3) << 16);
            *(uint2*)(Pb + (((kt * 32 + g * 8) ^ swz))) = pk;
        }
        rs += __shfl_xor(rs, 16, 64);
        rs += __shfl_xor(rs, 32, 64);
        lrow = lrow * alpha + rs;

        float af[4];
        #pragma unroll
        for (int j = 0; j < 4; ++j) af[j] = __shfl(alpha, g * 4 + j, 64);
        #pragma unroll
        for (int dt = 0; dt < 4; ++dt)
            #pragma unroll
            for (int j = 0; j < 4; ++j) o[dt][j] *= af[j];

        #pragma unroll
        for (int Bb = 0; Bb < 2; ++Bb) {
            const bf16x8 pa = *(const bf16x8*)(Pb + (((Bb * 64 + g * 16) ^ swz)));
            #pragma unroll
            for (int dt = 0; dt < 4; ++dt) {
                const bf16x8 vb = *(const bf16x8*)((char*)Vs + (dt * 16 + q15) * 128 +
                                                   ((Bb * 64 + g * 16) ^ swz));
                o[dt] = __builtin_amdgcn_mfma_f32_16x16x32_bf16(pa, vb, o[dt], 0, 0, 0);
            }
        }
        __syncthreads();
    }

    #pragma unroll
    for (int dt = 0; dt < 4; ++dt)
        #pragma unroll
        for (int j = 0; j < 4; ++j) {
            const int q = qbase + g * 4 + j;
            Op[(((size_t)z * 64 + bh) * 1024 + q) * 64 + dt * 16 + q15] = f2bf(o[dt][j]);
        }
    if (g == 0) {
        const size_t mi = ((size_t)z * 64 + bh) * 1024 + qbase + q15;
        Mws[mi] = mrow;
        Lws[mi] = lrow;
    }
}

// ---------------------------------------------------------------------------
// Combine the two kv-halves
// ---------------------------------------------------------------------------
__global__ __launch_bounds__(256)
void attn_combine(const unsigned short* __restrict__ Op,
                  const float* __restrict__ Mws,
                  const float* __restrict__ Lws,
                  unsigned short* __restrict__ Ob) {
    const int e4 = blockIdx.x * 256 + threadIdx.x;
    const int d0 = (e4 & 15) * 4;
    const int q  = (e4 >> 4) & 1023;
    const int bh = e4 >> 14;
    const size_t base0 = (((size_t)bh) * 1024 + q) * 64 + d0;
    const size_t base1 = (((size_t)(64 + bh)) * 1024 + q) * 64 + d0;
    const ushort4 a = *(const ushort4*)&Op[base0];
    const ushort4 c = *(const ushort4*)&Op[base1];
    const size_t mi0 = (size_t)bh * 1024 + q;
    const size_t mi1 = mi0 + 64 * 1024;
    const float m0 = Mws[mi0], m1 = Mws[mi1];
    const float l0 = Lws[mi0], l1 = Lws[mi1];
    const float m  = fmaxf(m0, m1);
    const float w0 = __expf(m0 - m), w1 = __expf(m1 - m);
    const float inv = 1.0f / (l0 * w0 + l1 * w1);
    ushort4 r;
    r.x = f2bf((bf2f(a.x) * w0 + bf2f(c.x) * w1) * inv);
    r.y = f2bf((bf2f(a.y) * w0 + bf2f(c.y) * w1) * inv);
    r.z = f2bf((bf2f(a.z) * w0 + bf2f(c.z) * w1) * inv);
    r.w = f2bf((bf2f(a.w) * w0 + bf2f(c.w) * w1) * inv);
    const int b = bh >> 4, h = bh & 15;
    *(ushort4*)&Ob[((size_t)(b * 1024 + q)) * 1024 + h * 64 + d0] = r;
}

// ---------------------------------------------------------------------------
// Launch  (final: R20/R22 best-known configuration, 253.0 us)
// ---------------------------------------------------------------------------
extern "C" void kernel_launch(void* const* d_in, const int* in_sizes, int n_in,
                              void* d_out, int out_size, void* d_ws, size_t ws_size,
                              hipStream_t stream) {
    (void)in_sizes; (void)n_in; (void)out_size; (void)ws_size;
    const float* x     = (const float*)d_in[0];
    const float* Qin   = (const float*)d_in[1];
    const float* Kin   = (const float*)d_in[2];
    const float* Vin   = (const float*)d_in[3];
    const float* ln_w  = (const float*)d_in[4];
    const float* ln_b  = (const float*)d_in[5];
    const float* qk_w  = (const float*)d_in[6];
    const float* qk_b  = (const float*)d_in[7];
    const float* v_w   = (const float*)d_in[8];
    const float* v_b   = (const float*)d_in[9];
    const float* out_w = (const float*)d_in[10];
    const float* out_b = (const float*)d_in[11];
    const float* w1    = (const float*)d_in[12];
    const float* b1    = (const float*)d_in[13];
    const float* w2    = (const float*)d_in[14];
    const float* b2    = (const float*)d_in[15];

    const size_t FOUR_M = (size_t)4 * 1024 * 1024;
    float* out0 = (float*)d_out;
    float* Qout = out0 + FOUR_M;
    float* Kout = Qout + FOUR_M;
    float* Vout = Kout + FOUR_M;

    char* ws = (char*)d_ws;
    const size_t MB = 1024 * 1024;
    unsigned short* xn   = (unsigned short*)(ws + 0);        // 8MB (reused as xn2)
    unsigned short* qkwb = (unsigned short*)(ws + 8 * MB);   // 4MB (dead after qk gemm)
    unsigned short* vwb  = (unsigned short*)(ws + 12 * MB);  // 2MB
    unsigned short* owb  = (unsigned short*)(ws + 14 * MB);  // 2MB
    unsigned short* w1b  = (unsigned short*)(ws + 16 * MB);  // 8MB
    unsigned short* w2b  = (unsigned short*)(ws + 24 * MB);  // 8MB
    unsigned short* Qbuf = (unsigned short*)(ws + 32 * MB);  // 8MB
    unsigned short* Kbuf = (unsigned short*)(ws + 40 * MB);  // 8MB
    unsigned short* Vtb  = (unsigned short*)(ws + 48 * MB);  // 8MB
    unsigned short* atto = (unsigned short*)(ws + 56 * MB);  // 8MB
    unsigned short* hbuf = (unsigned short*)(ws + 32 * MB);  // 32MB, reuses Q/K/V/atto after attn
    float* y1 = (float*)(ws + 64 * MB);                      // 16MB (after combine)
    unsigned short* Oprt = (unsigned short*)(ws + 64 * MB);  // 16MB partials (dead before y1)
    float* Mws = (float*)(ws + 8 * MB);                      // 512KB (reuses dead qkwb)
    float* Lws = (float*)(ws + 8 * MB + 512 * 1024);         // 512KB

    // fused weight converts (single launch: qk_w | v_w | out_w | w1 | w2)
    cvt5_kernel<<<12288, 256, 0, stream>>>(qk_w, qkwb, v_w, vwb, out_w, owb,
                                           w1, w1b, w2, w2b);

    // LN1
    ln_kernel<<<4096, 256, 0, stream>>>(x, ln_w, ln_b, xn);

    // qk projection + mixing
    {
        dim3 g(2048 / 128, 4096 / 128);   // 512 blocks
        gemm_bt<0><<<g, 256, 0, stream>>>(xn, qkwb, qk_b, 4096, 2048, 1024,
                                          Qin, Kin, Qout, Kout, Qbuf, Kbuf);
    }
    // v projection + mixing (+ transposed bf16 copy)
    {
        dim3 g(1024 / 128, 4096 / 128);   // 256 blocks
        gemm_bt<1><<<g, 256, 0, stream>>>(xn, vwb, v_b, 4096, 1024, 1024,
                                          Vin, nullptr, Vout, nullptr, Vtb, nullptr);
    }
    // attention (split-KV x2) + combine
    {
        dim3 g(16, 64, 2);
        attn_kernel<<<g, 256, 0, stream>>>(Qbuf, Kbuf, Vtb, Oprt, Mws, Lws);
        attn_combine<<<4096, 256, 0, stream>>>(Oprt, Mws, Lws, atto);
    }
    // out projection + residual -> y1
    {
        dim3 g(1024 / 128, 4096 / 128);   // 256 blocks
        gemm_bt<2><<<g, 256, 0, stream>>>(atto, owb, out_b, 4096, 1024, 1024,
                                          x, nullptr, y1, nullptr, nullptr, nullptr);
    }
    // LN2
    ln_kernel<<<4096, 256, 0, stream>>>(y1, ln_w, ln_b, xn);
    // MLP fc1 + GELU: pipelined 256x256 big kernel (256 blocks, 512 threads)
    {
        dim3 g(4096 / 256, 4096 / 256);
        gemm_big_gelu<<<g, 512, 0, stream>>>(xn, w1b, b1, 4096, 4096, 1024, hbuf);
    }
    // MLP fc2 + residual -> out0 (verified 128^2 path)
    {
        dim3 g(1024 / 128, 4096 / 128);   // 256 blocks
        gemm_bt<2><<<g, 256, 0, stream>>>(hbuf, w2b, b2, 4096, 1024, 4096,
                                          y1, nullptr, out0, nullptr, nullptr, nullptr);
    }
}